// Round 1
// baseline (3218.314 us; speedup 1.0000x reference)
//
#include <hip/hip_runtime.h>
#include <math.h>

#define BATCH 256
#define CIN 1280
#define COUT 128
#define S49 49
#define F1IN 6272
#define F1OUT 4096
#define F2OUT 1470
#define NBOX 98

// ---------------------------------------------------------------------------
// Stage 1: subsample + 1x1 conv as GEMM.  h1[b, o*49+s] = sum_c x[b,c,2i,2j]*w[o,c] + bias[o]
// grid (256 b, 2 o-tiles of 64), 256 threads = 64 o-lanes x 4 s-groups, fp64 acc.
// ---------------------------------------------------------------------------
__global__ __launch_bounds__(256) void conv_kernel(const float* __restrict__ x,
                                                   const float* __restrict__ w,
                                                   const float* __restrict__ bias,
                                                   double* __restrict__ h1) {
    const int b = blockIdx.x;
    const int obase = blockIdx.y * 64;
    const int tid = threadIdx.x;
    const int o_l = tid & 63;
    const int g = tid >> 6;          // 0..3, strided s coverage

    __shared__ float xs[128 * 49];   // [c][s] chunk
    __shared__ float wT[128 * 64];   // [c][o] chunk

    double acc[13];
#pragma unroll
    for (int k = 0; k < 13; ++k) acc[k] = 0.0;

    const float* xb = x + (size_t)b * CIN * 196;

    for (int cb = 0; cb < CIN; cb += 128) {
        __syncthreads();
        for (int idx = tid; idx < 128 * 49; idx += 256) {
            int c = idx / 49, s = idx - c * 49;
            int si = s / 7, sj = s - si * 7;
            xs[idx] = xb[(size_t)(cb + c) * 196 + si * 28 + sj * 2];
        }
        for (int idx = tid; idx < 128 * 64; idx += 256) {
            int o = idx >> 7, c = idx & 127;
            wT[c * 64 + o] = w[(size_t)(obase + o) * CIN + cb + c];
        }
        __syncthreads();
        for (int c = 0; c < 128; ++c) {
            double wv = (double)wT[c * 64 + o_l];
#pragma unroll
            for (int k = 0; k < 13; ++k) {
                int sg = g + 4 * k;
                if (sg < 49) acc[k] = fma(wv, (double)xs[c * 49 + sg], acc[k]);
            }
        }
    }

    const int o = obase + o_l;
    const double bv = (double)bias[o];
    for (int k = 0; k < 13; ++k) {
        int sg = g + 4 * k;
        if (sg < 49) h1[(size_t)b * F1IN + (size_t)o * 49 + sg] = acc[k] + bv;
    }
}

// ---------------------------------------------------------------------------
// FC GEMM (NT): C[m][n] = sum_k A[m][k] * W[n][k] + bias[n]   (fp64 acc)
// A: double MxK row-major, W: float NxK row-major, C: double MxN.
// 64x64 block tile, K-chunk 32, 256 threads with 4x4 micro-tiles.
// ---------------------------------------------------------------------------
template <bool LEAKY, bool NCHECK>
__global__ __launch_bounds__(256) void fc_kernel(const double* __restrict__ A,
                                                 const float* __restrict__ W,
                                                 const float* __restrict__ bias,
                                                 double* __restrict__ C,
                                                 int N, int K) {
    __shared__ double As[64][33];
    __shared__ float  Ws[64][33];

    const int mbase = blockIdx.x * 64;
    const int nbase = blockIdx.y * 64;
    const int tid = threadIdx.x;
    const int tm = tid >> 4;   // 0..15
    const int tn = tid & 15;   // 0..15

    double acc[4][4];
#pragma unroll
    for (int i = 0; i < 4; ++i)
#pragma unroll
        for (int j = 0; j < 4; ++j) acc[i][j] = 0.0;

    for (int kb = 0; kb < K; kb += 32) {
        __syncthreads();
        for (int idx = tid; idx < 64 * 32; idx += 256) {
            int r = idx >> 5, kk = idx & 31;
            As[r][kk] = A[(size_t)(mbase + r) * K + kb + kk];
        }
        for (int idx = tid; idx < 64 * 32; idx += 256) {
            int r = idx >> 5, kk = idx & 31;
            int n = nbase + r;
            Ws[r][kk] = (!NCHECK || n < N) ? W[(size_t)n * K + kb + kk] : 0.0f;
        }
        __syncthreads();
        for (int kk = 0; kk < 32; ++kk) {
            double a[4];
            float bw[4];
#pragma unroll
            for (int i = 0; i < 4; ++i) a[i] = As[tm * 4 + i][kk];
#pragma unroll
            for (int j = 0; j < 4; ++j) bw[j] = Ws[tn * 4 + j][kk];
#pragma unroll
            for (int i = 0; i < 4; ++i)
#pragma unroll
                for (int j = 0; j < 4; ++j)
                    acc[i][j] = fma(a[i], (double)bw[j], acc[i][j]);
        }
    }

#pragma unroll
    for (int i = 0; i < 4; ++i) {
        int m = mbase + tm * 4 + i;
#pragma unroll
        for (int j = 0; j < 4; ++j) {
            int n = nbase + tn * 4 + j;
            if (!NCHECK || n < N) {
                double v = acc[i][j] + (double)bias[n];
                if (LEAKY) v = (v >= 0.0) ? v : 0.1 * v;
                C[(size_t)m * N + n] = v;
            }
        }
    }
}

// ---------------------------------------------------------------------------
// Stage 4: sigmoid + decode + stable sort + greedy NMS + top-10. One block / image.
// ---------------------------------------------------------------------------
__global__ __launch_bounds__(128) void decode_nms_kernel(const double* __restrict__ Z,
                                                         float* __restrict__ out_boxes,
                                                         float* __restrict__ out_labels,
                                                         float* __restrict__ out_confs) {
    const int b = blockIdx.x;
    const int tid = threadIdx.x;

    __shared__ double sAll[F2OUT];
    __shared__ double bx[NBOX][4];
    __shared__ double cf[NBOX];
    __shared__ int lab[NBOX];
    __shared__ double sbx[NBOX][4];
    __shared__ double scf[NBOX];
    __shared__ int slab[NBOX];
    __shared__ unsigned long long suprow[NBOX][2];

    const double* z = Z + (size_t)b * F2OUT;
    for (int i = tid; i < F2OUT; i += 128)
        sAll[i] = 1.0 / (1.0 + exp(-z[i]));
    __syncthreads();

    // decode 98 boxes + labels
    for (int n = tid; n < NBOX; n += 128) {
        int gi = n / 14;
        int gj = (n % 14) >> 1;
        double cx = sAll[4 * n + 0] * 64.0 + 64.0 * (double)gi;
        double cy = sAll[4 * n + 1] * 64.0 + 64.0 * (double)gj;
        double w  = sAll[4 * n + 2] * 448.0;
        double hh = sAll[4 * n + 3] * 448.0;
        double x1 = cx - 0.5 * w,  y1 = cy - 0.5 * hh;
        double x2 = cx + 0.5 * w,  y2 = cy + 0.5 * hh;
        x1 = x1 < 0.0 ? 0.0 : (x1 > 448.0 ? 448.0 : x1);
        y1 = y1 < 0.0 ? 0.0 : (y1 > 448.0 ? 448.0 : y1);
        x2 = x2 < 0.0 ? 0.0 : (x2 > 448.0 ? 448.0 : x2);
        y2 = y2 < 0.0 ? 0.0 : (y2 > 448.0 ? 448.0 : y2);
        bx[n][0] = x1; bx[n][1] = y1; bx[n][2] = x2; bx[n][3] = y2;
        cf[n] = sAll[392 + n];
        int cell = n >> 1;
        double best = sAll[490 + cell * 20];
        int bl = 0;
        for (int c = 1; c < 20; ++c) {
            double v = sAll[490 + cell * 20 + c];
            if (v > best) { best = v; bl = c; }
        }
        lab[n] = bl;
    }
    __syncthreads();

    // stable descending sort by conf via rank counting
    for (int n = tid; n < NBOX; n += 128) {
        double cn = cf[n];
        int r = 0;
        for (int m = 0; m < NBOX; ++m) {
            double cm = cf[m];
            if (cm > cn || (cm == cn && m < n)) ++r;
        }
        scf[r] = cn;
        slab[r] = lab[n];
        sbx[r][0] = bx[n][0]; sbx[r][1] = bx[n][1];
        sbx[r][2] = bx[n][2]; sbx[r][3] = bx[n][3];
    }
    __syncthreads();

    // iou > 0.7 bitmask rows
    for (int i = tid; i < NBOX; i += 128) {
        double x1 = sbx[i][0], y1 = sbx[i][1], x2 = sbx[i][2], y2 = sbx[i][3];
        double ai = fmax(x2 - x1, 0.0) * fmax(y2 - y1, 0.0);
        unsigned long long m0 = 0ull, m1 = 0ull;
        for (int j = 0; j < NBOX; ++j) {
            double jx1 = sbx[j][0], jy1 = sbx[j][1], jx2 = sbx[j][2], jy2 = sbx[j][3];
            double xx1 = fmax(x1, jx1), yy1 = fmax(y1, jy1);
            double xx2 = fmin(x2, jx2), yy2 = fmin(y2, jy2);
            double inter = fmax(xx2 - xx1, 0.0) * fmax(yy2 - yy1, 0.0);
            double aj = fmax(jx2 - jx1, 0.0) * fmax(jy2 - jy1, 0.0);
            double uni = ai + aj - inter;
            double iou = (uni > 0.0) ? inter / uni : 0.0;
            if (iou > 0.7) {
                if (j < 64) m0 |= 1ull << j;
                else        m1 |= 1ull << (j - 64);
            }
        }
        suprow[i][0] = m0;
        suprow[i][1] = m1;
    }
    __syncthreads();

    if (tid == 0) {
        unsigned long long k0 = 0ull, k1 = 0ull;
        for (int i = 0; i < NBOX; ++i) {
            if (scf[i] > 0.1) {
                if (i < 64) k0 |= 1ull << i;
                else        k1 |= 1ull << (i - 64);
            }
        }
        for (int i = 0; i < NBOX; ++i) {
            bool ki = (i < 64) ? ((k0 >> i) & 1ull) : ((k1 >> (i - 64)) & 1ull);
            if (!ki) continue;
            unsigned long long g0, g1;
            if (i < 63)       { g0 = (~0ull) << (i + 1); g1 = ~0ull; }
            else if (i == 63) { g0 = 0ull;               g1 = ~0ull; }
            else              { g0 = 0ull;               g1 = (~0ull) << (i - 63); }
            k0 &= ~(suprow[i][0] & g0);
            k1 &= ~(suprow[i][1] & g1);
        }
        int cnt = 0;
        for (int i = 0; i < NBOX && cnt < 10; ++i) {
            bool ki = (i < 64) ? ((k0 >> i) & 1ull) : ((k1 >> (i - 64)) & 1ull);
            if (!ki) continue;
            out_boxes[(size_t)b * 40 + cnt * 4 + 0] = (float)sbx[i][0];
            out_boxes[(size_t)b * 40 + cnt * 4 + 1] = (float)sbx[i][1];
            out_boxes[(size_t)b * 40 + cnt * 4 + 2] = (float)sbx[i][2];
            out_boxes[(size_t)b * 40 + cnt * 4 + 3] = (float)sbx[i][3];
            out_labels[b * 10 + cnt] = (float)slab[i];
            out_confs[b * 10 + cnt]  = (float)scf[i];
            ++cnt;
        }
        for (; cnt < 10; ++cnt) {
            out_boxes[(size_t)b * 40 + cnt * 4 + 0] = 0.0f;
            out_boxes[(size_t)b * 40 + cnt * 4 + 1] = 0.0f;
            out_boxes[(size_t)b * 40 + cnt * 4 + 2] = 0.0f;
            out_boxes[(size_t)b * 40 + cnt * 4 + 3] = 0.0f;
            out_labels[b * 10 + cnt] = 0.0f;
            out_confs[b * 10 + cnt]  = 0.0f;
        }
    }
}

extern "C" void kernel_launch(void* const* d_in, const int* in_sizes, int n_in,
                              void* d_out, int out_size, void* d_ws, size_t ws_size,
                              hipStream_t stream) {
    const float* x      = (const float*)d_in[0];
    const float* conv_w = (const float*)d_in[1];
    const float* conv_b = (const float*)d_in[2];
    const float* fc1_w  = (const float*)d_in[3];
    const float* fc1_b  = (const float*)d_in[4];
    const float* fc2_w  = (const float*)d_in[5];
    const float* fc2_b  = (const float*)d_in[6];

    double* h1 = (double*)d_ws;                       // 256 x 6272
    double* a1 = h1 + (size_t)BATCH * F1IN;           // 256 x 4096
    double* a2 = a1 + (size_t)BATCH * F1OUT;          // 256 x 1470

    float* out_boxes  = (float*)d_out;                // 256*10*4
    float* out_labels = out_boxes + (size_t)BATCH * 40;   // 256*10
    float* out_confs  = out_labels + (size_t)BATCH * 10;  // 256*10

    conv_kernel<<<dim3(BATCH, 2), 256, 0, stream>>>(x, conv_w, conv_b, h1);
    fc_kernel<true, false><<<dim3(4, 64), 256, 0, stream>>>(h1, fc1_w, fc1_b, a1, F1OUT, F1IN);
    fc_kernel<false, true><<<dim3(4, 23), 256, 0, stream>>>(a1, fc2_w, fc2_b, a2, F2OUT, F1OUT);
    decode_nms_kernel<<<BATCH, 128, 0, stream>>>(a2, out_boxes, out_labels, out_confs);
}

// Round 2
// 1570.947 us; speedup vs baseline: 2.0486x; 2.0486x over previous
//
#include <hip/hip_runtime.h>
#include <math.h>

#define BATCH 256
#define CIN 1280
#define COUT 128
#define F1IN 6272
#define F1OUT 4096
#define F2OUT 1470
#define NBOX 98

// ---------------------------------------------------------------------------
// Stage 1: subsample + 1x1 conv as GEMM.  h1[b, o*49+s] = sum_c x[b,c,2i,2j]*w[o,c] + bias[o]
// ---------------------------------------------------------------------------
__global__ __launch_bounds__(256) void conv_kernel(const float* __restrict__ x,
                                                   const float* __restrict__ w,
                                                   const float* __restrict__ bias,
                                                   double* __restrict__ h1) {
    const int b = blockIdx.x;
    const int obase = blockIdx.y * 64;
    const int tid = threadIdx.x;
    const int o_l = tid & 63;
    const int g = tid >> 6;          // 0..3, strided s coverage

    __shared__ float xs[128 * 49];   // [c][s] chunk
    __shared__ float wT[128 * 64];   // [c][o] chunk

    double acc[13];
#pragma unroll
    for (int k = 0; k < 13; ++k) acc[k] = 0.0;

    const float* xb = x + (size_t)b * CIN * 196;

    for (int cb = 0; cb < CIN; cb += 128) {
        __syncthreads();
        for (int idx = tid; idx < 128 * 49; idx += 256) {
            int c = idx / 49, s = idx - c * 49;
            int si = s / 7, sj = s - si * 7;
            xs[idx] = xb[(size_t)(cb + c) * 196 + si * 28 + sj * 2];
        }
        for (int idx = tid; idx < 128 * 64; idx += 256) {
            int o = idx >> 7, c = idx & 127;
            wT[c * 64 + o] = w[(size_t)(obase + o) * CIN + cb + c];
        }
        __syncthreads();
        for (int c = 0; c < 128; ++c) {
            double wv = (double)wT[c * 64 + o_l];
#pragma unroll
            for (int k = 0; k < 13; ++k) {
                int sg = g + 4 * k;
                if (sg < 49) acc[k] = fma(wv, (double)xs[c * 49 + sg], acc[k]);
            }
        }
    }

    const int o = obase + o_l;
    const double bv = (double)bias[o];
    for (int k = 0; k < 13; ++k) {
        int sg = g + 4 * k;
        if (sg < 49) h1[(size_t)b * F1IN + (size_t)o * 49 + sg] = acc[k] + bv;
    }
}

// ---------------------------------------------------------------------------
// FC GEMM split-K (NT): partial C[m][n] += sum_{k in chunk} A[m][k]*W[n][k]
// A: double MxK row-major, W: float NxK row-major. C pre-zeroed; fp64 atomicAdd.
// 64x64 tile, K-chunk 32, 256 threads, 4x4 micro. blockIdx.z selects K-slice.
// ---------------------------------------------------------------------------
template <bool NCHECK>
__global__ __launch_bounds__(256) void fc_splitk_kernel(const double* __restrict__ A,
                                                        const float* __restrict__ W,
                                                        double* __restrict__ C,
                                                        int N, int K, int kchunks_per_slice) {
    __shared__ double As[64][33];
    __shared__ float  Ws[64][33];

    const int mbase = blockIdx.x * 64;
    const int nbase = blockIdx.y * 64;
    const int kb0 = blockIdx.z * kchunks_per_slice * 32;
    const int kb1 = kb0 + kchunks_per_slice * 32;
    const int tid = threadIdx.x;
    const int tm = tid >> 4;   // 0..15
    const int tn = tid & 15;   // 0..15

    double acc[4][4];
#pragma unroll
    for (int i = 0; i < 4; ++i)
#pragma unroll
        for (int j = 0; j < 4; ++j) acc[i][j] = 0.0;

    for (int kb = kb0; kb < kb1; kb += 32) {
        __syncthreads();
        for (int idx = tid; idx < 64 * 32; idx += 256) {
            int r = idx >> 5, kk = idx & 31;
            As[r][kk] = A[(size_t)(mbase + r) * K + kb + kk];
        }
        for (int idx = tid; idx < 64 * 32; idx += 256) {
            int r = idx >> 5, kk = idx & 31;
            int n = nbase + r;
            Ws[r][kk] = (!NCHECK || n < N) ? W[(size_t)n * K + kb + kk] : 0.0f;
        }
        __syncthreads();
        for (int kk = 0; kk < 32; ++kk) {
            double a[4];
            float bw[4];
#pragma unroll
            for (int i = 0; i < 4; ++i) a[i] = As[tm * 4 + i][kk];
#pragma unroll
            for (int j = 0; j < 4; ++j) bw[j] = Ws[tn * 4 + j][kk];
#pragma unroll
            for (int i = 0; i < 4; ++i)
#pragma unroll
                for (int j = 0; j < 4; ++j)
                    acc[i][j] = fma(a[i], (double)bw[j], acc[i][j]);
        }
    }

#pragma unroll
    for (int i = 0; i < 4; ++i) {
        int m = mbase + tm * 4 + i;
#pragma unroll
        for (int j = 0; j < 4; ++j) {
            int n = nbase + tn * 4 + j;
            if (!NCHECK || n < N)
                atomicAdd(&C[(size_t)m * N + n], acc[i][j]);
        }
    }
}

// epilogue: C += bias, optional leaky relu
template <bool LEAKY>
__global__ __launch_bounds__(256) void bias_act_kernel(double* __restrict__ C,
                                                       const float* __restrict__ bias,
                                                       int N, size_t total) {
    size_t idx = (size_t)blockIdx.x * 256 + threadIdx.x;
    if (idx >= total) return;
    int n = (int)(idx % (size_t)N);
    double v = C[idx] + (double)bias[n];
    if (LEAKY) v = (v >= 0.0) ? v : 0.1 * v;
    C[idx] = v;
}

// ---------------------------------------------------------------------------
// Stage 4: sigmoid + decode + stable sort + greedy NMS + top-10. One block / image.
// ---------------------------------------------------------------------------
__global__ __launch_bounds__(128) void decode_nms_kernel(const double* __restrict__ Z,
                                                         float* __restrict__ out_boxes,
                                                         float* __restrict__ out_labels,
                                                         float* __restrict__ out_confs) {
    const int b = blockIdx.x;
    const int tid = threadIdx.x;

    __shared__ double sAll[F2OUT];
    __shared__ double bx[NBOX][4];
    __shared__ double cf[NBOX];
    __shared__ int lab[NBOX];
    __shared__ double sbx[NBOX][4];
    __shared__ double scf[NBOX];
    __shared__ int slab[NBOX];
    __shared__ unsigned long long suprow[NBOX][2];

    const double* z = Z + (size_t)b * F2OUT;
    for (int i = tid; i < F2OUT; i += 128)
        sAll[i] = 1.0 / (1.0 + exp(-z[i]));
    __syncthreads();

    // decode 98 boxes + labels
    for (int n = tid; n < NBOX; n += 128) {
        int gi = n / 14;
        int gj = (n % 14) >> 1;
        double cx = sAll[4 * n + 0] * 64.0 + 64.0 * (double)gi;
        double cy = sAll[4 * n + 1] * 64.0 + 64.0 * (double)gj;
        double w  = sAll[4 * n + 2] * 448.0;
        double hh = sAll[4 * n + 3] * 448.0;
        double x1 = cx - 0.5 * w,  y1 = cy - 0.5 * hh;
        double x2 = cx + 0.5 * w,  y2 = cy + 0.5 * hh;
        x1 = x1 < 0.0 ? 0.0 : (x1 > 448.0 ? 448.0 : x1);
        y1 = y1 < 0.0 ? 0.0 : (y1 > 448.0 ? 448.0 : y1);
        x2 = x2 < 0.0 ? 0.0 : (x2 > 448.0 ? 448.0 : x2);
        y2 = y2 < 0.0 ? 0.0 : (y2 > 448.0 ? 448.0 : y2);
        bx[n][0] = x1; bx[n][1] = y1; bx[n][2] = x2; bx[n][3] = y2;
        cf[n] = sAll[392 + n];
        int cell = n >> 1;
        double best = sAll[490 + cell * 20];
        int bl = 0;
        for (int c = 1; c < 20; ++c) {
            double v = sAll[490 + cell * 20 + c];
            if (v > best) { best = v; bl = c; }
        }
        lab[n] = bl;
    }
    __syncthreads();

    // stable descending sort by conf via rank counting
    for (int n = tid; n < NBOX; n += 128) {
        double cn = cf[n];
        int r = 0;
        for (int m = 0; m < NBOX; ++m) {
            double cm = cf[m];
            if (cm > cn || (cm == cn && m < n)) ++r;
        }
        scf[r] = cn;
        slab[r] = lab[n];
        sbx[r][0] = bx[n][0]; sbx[r][1] = bx[n][1];
        sbx[r][2] = bx[n][2]; sbx[r][3] = bx[n][3];
    }
    __syncthreads();

    // iou > 0.7 bitmask rows
    for (int i = tid; i < NBOX; i += 128) {
        double x1 = sbx[i][0], y1 = sbx[i][1], x2 = sbx[i][2], y2 = sbx[i][3];
        double ai = fmax(x2 - x1, 0.0) * fmax(y2 - y1, 0.0);
        unsigned long long m0 = 0ull, m1 = 0ull;
        for (int j = 0; j < NBOX; ++j) {
            double jx1 = sbx[j][0], jy1 = sbx[j][1], jx2 = sbx[j][2], jy2 = sbx[j][3];
            double xx1 = fmax(x1, jx1), yy1 = fmax(y1, jy1);
            double xx2 = fmin(x2, jx2), yy2 = fmin(y2, jy2);
            double inter = fmax(xx2 - xx1, 0.0) * fmax(yy2 - yy1, 0.0);
            double aj = fmax(jx2 - jx1, 0.0) * fmax(jy2 - jy1, 0.0);
            double uni = ai + aj - inter;
            double iou = (uni > 0.0) ? inter / uni : 0.0;
            if (iou > 0.7) {
                if (j < 64) m0 |= 1ull << j;
                else        m1 |= 1ull << (j - 64);
            }
        }
        suprow[i][0] = m0;
        suprow[i][1] = m1;
    }
    __syncthreads();

    if (tid == 0) {
        unsigned long long k0 = 0ull, k1 = 0ull;
        for (int i = 0; i < NBOX; ++i) {
            if (scf[i] > 0.1) {
                if (i < 64) k0 |= 1ull << i;
                else        k1 |= 1ull << (i - 64);
            }
        }
        for (int i = 0; i < NBOX; ++i) {
            bool ki = (i < 64) ? ((k0 >> i) & 1ull) : ((k1 >> (i - 64)) & 1ull);
            if (!ki) continue;
            unsigned long long g0, g1;
            if (i < 63)       { g0 = (~0ull) << (i + 1); g1 = ~0ull; }
            else if (i == 63) { g0 = 0ull;               g1 = ~0ull; }
            else              { g0 = 0ull;               g1 = (~0ull) << (i - 63); }
            k0 &= ~(suprow[i][0] & g0);
            k1 &= ~(suprow[i][1] & g1);
        }
        int cnt = 0;
        for (int i = 0; i < NBOX && cnt < 10; ++i) {
            bool ki = (i < 64) ? ((k0 >> i) & 1ull) : ((k1 >> (i - 64)) & 1ull);
            if (!ki) continue;
            out_boxes[(size_t)b * 40 + cnt * 4 + 0] = (float)sbx[i][0];
            out_boxes[(size_t)b * 40 + cnt * 4 + 1] = (float)sbx[i][1];
            out_boxes[(size_t)b * 40 + cnt * 4 + 2] = (float)sbx[i][2];
            out_boxes[(size_t)b * 40 + cnt * 4 + 3] = (float)sbx[i][3];
            out_labels[b * 10 + cnt] = (float)slab[i];
            out_confs[b * 10 + cnt]  = (float)scf[i];
            ++cnt;
        }
        for (; cnt < 10; ++cnt) {
            out_boxes[(size_t)b * 40 + cnt * 4 + 0] = 0.0f;
            out_boxes[(size_t)b * 40 + cnt * 4 + 1] = 0.0f;
            out_boxes[(size_t)b * 40 + cnt * 4 + 2] = 0.0f;
            out_boxes[(size_t)b * 40 + cnt * 4 + 3] = 0.0f;
            out_labels[b * 10 + cnt] = 0.0f;
            out_confs[b * 10 + cnt]  = 0.0f;
        }
    }
}

extern "C" void kernel_launch(void* const* d_in, const int* in_sizes, int n_in,
                              void* d_out, int out_size, void* d_ws, size_t ws_size,
                              hipStream_t stream) {
    const float* x      = (const float*)d_in[0];
    const float* conv_w = (const float*)d_in[1];
    const float* conv_b = (const float*)d_in[2];
    const float* fc1_w  = (const float*)d_in[3];
    const float* fc1_b  = (const float*)d_in[4];
    const float* fc2_w  = (const float*)d_in[5];
    const float* fc2_b  = (const float*)d_in[6];

    double* h1 = (double*)d_ws;                       // 256 x 6272
    double* a1 = h1 + (size_t)BATCH * F1IN;           // 256 x 4096
    double* a2 = a1 + (size_t)BATCH * F1OUT;          // 256 x 1470

    float* out_boxes  = (float*)d_out;                // 256*10*4
    float* out_labels = out_boxes + (size_t)BATCH * 40;   // 256*10
    float* out_confs  = out_labels + (size_t)BATCH * 10;  // 256*10

    // zero the atomic-accumulated outputs (graph-capture-legal)
    hipMemsetAsync(a1, 0, (size_t)BATCH * F1OUT * sizeof(double), stream);
    hipMemsetAsync(a2, 0, (size_t)BATCH * F2OUT * sizeof(double), stream);

    conv_kernel<<<dim3(BATCH, 2), 256, 0, stream>>>(x, conv_w, conv_b, h1);

    // FC1: M=256,N=4096,K=6272 -> 196 k-chunks, split 4 ways (49 each) = 1024 blocks
    fc_splitk_kernel<false><<<dim3(4, 64, 4), 256, 0, stream>>>(h1, fc1_w, a1, F1OUT, F1IN, 49);
    {
        size_t total = (size_t)BATCH * F1OUT;
        bias_act_kernel<true><<<(int)((total + 255) / 256), 256, 0, stream>>>(a1, fc1_b, F1OUT, total);
    }

    // FC2: M=256,N=1470,K=4096 -> 128 k-chunks, split 8 ways (16 each) = 736 blocks
    fc_splitk_kernel<true><<<dim3(4, 23, 8), 256, 0, stream>>>(a1, fc2_w, a2, F2OUT, F1OUT, 16);
    {
        size_t total = (size_t)BATCH * F2OUT;
        bias_act_kernel<false><<<(int)((total + 255) / 256), 256, 0, stream>>>(a2, fc2_b, F2OUT, total);
    }

    decode_nms_kernel<<<BATCH, 128, 0, stream>>>(a2, out_boxes, out_labels, out_confs);
}